// Round 7
// baseline (146.913 us; speedup 1.0000x reference)
//
#include <hip/hip_runtime.h>
#include <cstdint>
#include <cstddef>

#define B_ 4
#define N_ 4096
#define DIN_ 128

// c = log2(e)/8 ; C2 = c^2 ; exp(dist/8) = exp2(sqrt(d2 * C2))
#define C2_ 0.0325213905f
#define NEG2C2_ (-0.0650427810f)

typedef __attribute__((ext_vector_type(8))) short short8;
typedef __attribute__((ext_vector_type(4))) float f32x4;
typedef __attribute__((ext_vector_type(4))) unsigned short us4;

__device__ __forceinline__ unsigned short f2bf(float f) {
    union { float f; unsigned int i; } v; v.f = f;
    unsigned int i = v.i;
    return (unsigned short)((i + 0x7FFFu + ((i >> 16) & 1u)) >> 16);
}

__device__ __forceinline__ unsigned int cvt_pk_bf16(float lo, float hi) {
    unsigned int r;
    asm("v_cvt_pk_bf16_f32 %0, %1, %2" : "=v"(r) : "v"(lo), "v"(hi));
    return r;
}

// ---------------- projection: x[R,128] @ {Wq,Wk,Wv}[128,64] ----------------
// grid (256 row-tiles, 3 projs), 256 threads. Whole W (32KB) + x tile (33KB)
// staged in LDS; thread computes 4 rows x 4 cols, FMA-bound.
__global__ __launch_bounds__(256, 2) void proj_kernel(
    const float* __restrict__ x, const float* __restrict__ Wq,
    const float* __restrict__ Wk, const float* __restrict__ Wv,
    unsigned short* __restrict__ qb, unsigned short* __restrict__ kb,
    unsigned short* __restrict__ vT, float* __restrict__ qsq,
    float* __restrict__ ksq)
{
    __shared__ float xl[64 * 132];
    __shared__ float wl[128 * 64];
    const int t = threadIdx.x;
    const int R0 = blockIdx.x * 64;
    const int proj = blockIdx.y;
    const float* __restrict__ W = (proj == 0) ? Wq : ((proj == 1) ? Wk : Wv);

#pragma unroll
    for (int j = 0; j < 8; ++j) {
        const int i = t + 256 * j;
        const int row = i >> 5, dc = i & 31;
        *(float4*)(&xl[row * 132 + dc * 4]) =
            *(const float4*)(x + (size_t)(R0 + row) * DIN_ + dc * 4);
    }
#pragma unroll
    for (int j = 0; j < 8; ++j) {
        const int i = t + 256 * j;
        *(float4*)(&wl[i * 4]) = *(const float4*)(W + (size_t)i * 4);
    }
    __syncthreads();

    const int cg = t & 15, rg = t >> 4;
    const int c0 = cg * 4, r0 = rg * 4;

    float acc[4][4];
#pragma unroll
    for (int r = 0; r < 4; ++r)
#pragma unroll
        for (int c = 0; c < 4; ++c) acc[r][c] = 0.f;

    for (int d4 = 0; d4 < 32; ++d4) {
        float4 xv[4];
#pragma unroll
        for (int r = 0; r < 4; ++r)
            xv[r] = *(const float4*)(&xl[(r0 + r) * 132 + d4 * 4]);
#pragma unroll
        for (int dd = 0; dd < 4; ++dd) {
            const float4 wv = *(const float4*)(&wl[(d4 * 4 + dd) * 64 + c0]);
            const float wc[4] = { wv.x, wv.y, wv.z, wv.w };
#pragma unroll
            for (int r = 0; r < 4; ++r) {
                const float xr = ((const float*)&xv[r])[dd];
#pragma unroll
                for (int c = 0; c < 4; ++c)
                    acc[r][c] = fmaf(xr, wc[c], acc[r][c]);
            }
        }
    }

    if (proj < 2) {
        unsigned short* dst0 = (proj == 0) ? qb : kb;
#pragma unroll
        for (int r = 0; r < 4; ++r) {
            us4 pk = { f2bf(acc[r][0]), f2bf(acc[r][1]),
                       f2bf(acc[r][2]), f2bf(acc[r][3]) };
            *(us4*)(dst0 + (size_t)(R0 + r0 + r) * 64 + c0) = pk;
        }
#pragma unroll
        for (int r = 0; r < 4; ++r) {
            float s = 0.f;
#pragma unroll
            for (int c = 0; c < 4; ++c) s = fmaf(acc[r][c], acc[r][c], s);
            s += __shfl_xor(s, 1);
            s += __shfl_xor(s, 2);
            s += __shfl_xor(s, 4);
            s += __shfl_xor(s, 8);
            if (cg == 0) {
                float* sq = (proj == 0) ? qsq : ksq;
                sq[R0 + r0 + r] = s;
            }
        }
    } else {
        const int bb = R0 >> 12;
        const int n0 = (R0 & (N_ - 1)) + r0;
#pragma unroll
        for (int c = 0; c < 4; ++c) {
            us4 pk = { f2bf(acc[0][c]), f2bf(acc[1][c]),
                       f2bf(acc[2][c]), f2bf(acc[3][c]) };
            *(us4*)(vT + ((size_t)bb * 64 + (c0 + c)) * N_ + n0) = pk;
        }
    }
}

// ---------------- split-K flash attention, swapped QK^T, 8-wave blocks ----
// grid (32 q-tiles, 4 batch, 8 splits) = 1024 blocks = 4/CU; 512 threads =
// 8 waves x 16 q-rows. T14: next tile's K/V/ksq prefetched into REGISTERS at
// compute top; between the two barriers only ds_writes remain (global
// latency hidden under compute). T5: setprio around MFMA clusters.
__global__ __launch_bounds__(512, 8) void attn_kernel(
    const unsigned short* __restrict__ qb, const unsigned short* __restrict__ kb,
    const unsigned short* __restrict__ vT, const float* __restrict__ qsq,
    const float* __restrict__ ksq, float* __restrict__ Opart,
    float* __restrict__ Lpart, int ktn)
{
    __shared__ __align__(16) char smem[8192 * 2 + 16384 + 256];
    char* Klds = smem;                  // [64 k][64 d] bf16, XOR-swizzled rows
    char* Vlds = smem + 8192;           // [64 e][64 k] bf16, XOR-swizzled rows
    char* Plds = smem + 16384;          // 8 waves x [16 q][64 k] bf16, swizzled
    float* ksql = (float*)(smem + 32768);   // 64 f32, pre-scaled by C2

    const int t = threadIdx.x;
    const int w = t >> 6, lane = t & 63, li = lane & 15, g = lane >> 4;
    const int b = blockIdx.y, sp = blockIdx.z;
    const int q0 = blockIdx.x * 128;
    const int kt0 = sp * ktn;
    char* Pw = Plds + w * 2048;

    // Q fragment: lane li holds row (q0+w*16+li), d-slices g*8 and 32+g*8.
    // Used as the MFMA *B* operand in the swapped product.
    const size_t qoff = ((size_t)b * N_ + q0 + w * 16 + li) * 64;
    const short8 qa0 = *(const short8*)(qb + qoff + g * 8);
    const short8 qa1 = *(const short8*)(qb + qoff + 32 + g * 8);
    const float qsc = qsq[(size_t)b * N_ + q0 + w * 16 + li] * C2_;

    f32x4 oa[4];
#pragma unroll
    for (int i = 0; i < 4; ++i) oa[i] = (f32x4){0.f, 0.f, 0.f, 0.f};
    float lsum = 0.f;

    const unsigned short* kbb = kb + (size_t)b * N_ * 64;
    const unsigned short* vtb = vT + (size_t)b * 64 * N_;
    const float* ksqb = ksq + (size_t)b * N_;

    // staging: 512 16B-chunks each for K and V; thread t does one of each.
    const int row0 = t >> 3, cc0 = t & 7;
    const int lb0 = (row0 * 128 + cc0 * 16) ^ ((row0 & 7) << 4);

    // ---- prologue: stage tile kt0 ----
    *(uint4*)(Klds + lb0) = *(const uint4*)(kbb + (size_t)(kt0 * 64 + row0) * 64 + cc0 * 8);
    *(uint4*)(Vlds + lb0) = *(const uint4*)(vtb + (size_t)row0 * N_ + kt0 * 64 + cc0 * 8);
    if (t < 64) ksql[t] = ksqb[kt0 * 64 + t] * C2_;
    __syncthreads();

    for (int ktl = 0; ktl < ktn; ++ktl) {
        // ---- T14: issue next tile's global loads into registers ----
        const bool more = (ktl + 1 < ktn);
        uint4 kn = {0, 0, 0, 0}, vn = {0, 0, 0, 0};
        float ksn = 0.f;
        if (more) {
            const int kt1 = kt0 + ktl + 1;
            kn = *(const uint4*)(kbb + (size_t)(kt1 * 64 + row0) * 64 + cc0 * 8);
            vn = *(const uint4*)(vtb + (size_t)row0 * N_ + kt1 * 64 + cc0 * 8);
            if (t < 64) ksn = ksqb[kt1 * 64 + t] * C2_;
        }

        // ---- S^T = K Q^T (swapped): s[r] = S[k=c*16+g*4+r][q=li] ----
#pragma unroll
        for (int c = 0; c < 4; ++c) {
            const int kr = c * 16 + li;
            const int sw = (kr & 7) << 4;
            const short8 kf0 = *(const short8*)(Klds + ((kr * 128 + g * 16) ^ sw));
            const short8 kf1 = *(const short8*)(Klds + ((kr * 128 + 64 + g * 16) ^ sw));
            f32x4 s = (f32x4){0.f, 0.f, 0.f, 0.f};
            __builtin_amdgcn_s_setprio(1);
            s = __builtin_amdgcn_mfma_f32_16x16x32_bf16(kf0, qa0, s, 0, 0, 0);
            s = __builtin_amdgcn_mfma_f32_16x16x32_bf16(kf1, qa1, s, 0, 0, 0);
            __builtin_amdgcn_s_setprio(0);

            const float4 ksc = *(const float4*)(ksql + c * 16 + g * 4);
            const float kscv[4] = { ksc.x, ksc.y, ksc.z, ksc.w };
            float p[4];
#pragma unroll
            for (int r = 0; r < 4; ++r) {
                const float d2 = fmaf(NEG2C2_, s[r], qsc + kscv[r]);
                const float ds = __builtin_amdgcn_sqrtf(fmaxf(d2, 0.0f));
                p[r] = exp2f(ds);
                lsum += p[r];
            }
            // packed P write: row li, k-bytes c*32+g*8 .. +7
            uint2 pk;
            pk.x = cvt_pk_bf16(p[0], p[1]);
            pk.y = cvt_pk_bf16(p[2], p[3]);
            *(uint2*)(Pw + ((li * 128 + c * 32 + g * 8) ^ ((li & 7) << 4))) = pk;
        }

        // ---- O += P @ V : A = P[q=li][k g*8+j], B = V frags ----
        const int swp = (li & 7) << 4;
        const short8 pa0 = *(const short8*)(Pw + ((li * 128 + g * 16) ^ swp));
        const short8 pa1 = *(const short8*)(Pw + ((li * 128 + 64 + g * 16) ^ swp));
        __builtin_amdgcn_s_setprio(1);
#pragma unroll
        for (int c2 = 0; c2 < 4; ++c2) {
            const int er = c2 * 16 + li;
            const int swv = (er & 7) << 4;
            const short8 vf0 = *(const short8*)(Vlds + ((er * 128 + g * 16) ^ swv));
            const short8 vf1 = *(const short8*)(Vlds + ((er * 128 + 64 + g * 16) ^ swv));
            oa[c2] = __builtin_amdgcn_mfma_f32_16x16x32_bf16(pa0, vf0, oa[c2], 0, 0, 0);
            oa[c2] = __builtin_amdgcn_mfma_f32_16x16x32_bf16(pa1, vf1, oa[c2], 0, 0, 0);
        }
        __builtin_amdgcn_s_setprio(0);
        __syncthreads();   // all waves done reading K/V

        if (more) {
            *(uint4*)(Klds + lb0) = kn;
            *(uint4*)(Vlds + lb0) = vn;
            if (t < 64) ksql[t] = ksn;
            __syncthreads();   // publish next tile
        }
    }

    // ---- write partials (unnormalized) ----
    const size_t obase = ((size_t)sp * B_ + b) * N_;
    lsum += __shfl_xor(lsum, 16);
    lsum += __shfl_xor(lsum, 32);
    if (lane < 16) Lpart[obase + q0 + w * 16 + li] = lsum;
#pragma unroll
    for (int c2 = 0; c2 < 4; ++c2)
#pragma unroll
        for (int r = 0; r < 4; ++r)
            Opart[(obase + q0 + w * 16 + g * 4 + r) * 64 + c2 * 16 + li] = oa[c2][r];
}

// ---------------- combine splits + normalize ----------------
__global__ __launch_bounds__(256) void reduce_kernel(
    const float* __restrict__ Opart, const float* __restrict__ Lpart,
    float* __restrict__ out, int S)
{
    const int idx = blockIdx.x * 256 + threadIdx.x;
    const int rowg = idx >> 4;
    const int e4 = (idx & 15) << 2;
    float l = 0.f;
    float4 o = {0.f, 0.f, 0.f, 0.f};
    for (int s = 0; s < S; ++s) {
        l += Lpart[(size_t)s * (B_ * N_) + rowg];
        const float4 v = *(const float4*)(Opart + ((size_t)s * (B_ * N_) + rowg) * 64 + e4);
        o.x += v.x; o.y += v.y; o.z += v.z; o.w += v.w;
    }
    const float inv = 1.0f / l;
    const float4 res = {o.x * inv, o.y * inv, o.z * inv, o.w * inv};
    *(float4*)(out + (size_t)rowg * 64 + e4) = res;
}

extern "C" void kernel_launch(void* const* d_in, const int* in_sizes, int n_in,
                              void* d_out, int out_size, void* d_ws, size_t ws_size,
                              hipStream_t stream) {
    (void)in_sizes; (void)n_in; (void)out_size;
    const float* x  = (const float*)d_in[0];
    const float* Wq = (const float*)d_in[1];
    const float* Wk = (const float*)d_in[2];
    const float* Wv = (const float*)d_in[3];

    char* ws = (char*)d_ws;
    const size_t MB = 1024 * 1024;
    unsigned short* qb = (unsigned short*)(ws);                 // 2 MB
    unsigned short* kb = (unsigned short*)(ws + 2 * MB);        // 2 MB
    unsigned short* vT = (unsigned short*)(ws + 4 * MB);        // 2 MB
    float* qsq = (float*)(ws + 6 * MB);                         // 64 KB
    float* ksq = (float*)(ws + 6 * MB + 65536);                 // 64 KB
    float* Lpart = (float*)(ws + 6 * MB + 262144);              // <= 512 KB

    int S;
    float* Opart;
    if (ws_size >= 7 * MB + 32 * MB)      { S = 8; Opart = (float*)(ws + 7 * MB); }
    else if (ws_size >= 7 * MB + 16 * MB) { S = 4; Opart = (float*)(ws + 7 * MB); }
    else if (ws_size >= 7 * MB + 8 * MB)  { S = 2; Opart = (float*)(ws + 7 * MB); }
    else if (ws_size >= 7 * MB + 4 * MB)  { S = 1; Opart = (float*)(ws + 7 * MB); }
    else                                  { S = 1; Opart = (float*)d_out; }

    hipLaunchKernelGGL(proj_kernel, dim3(256, 3), dim3(256), 0, stream,
                       x, Wq, Wk, Wv, qb, kb, vT, qsq, ksq);
    hipLaunchKernelGGL(attn_kernel, dim3(32, B_, S), dim3(512), 0, stream,
                       qb, kb, vT, qsq, ksq, Opart, Lpart, 64 / S);
    hipLaunchKernelGGL(reduce_kernel, dim3(1024), dim3(256), 0, stream,
                       Opart, Lpart, (float*)d_out, S);
}

// Round 8
// 74.410 us; speedup vs baseline: 1.9744x; 1.9744x over previous
//
#include <hip/hip_runtime.h>
#include <cstdint>
#include <cstddef>

#define B_ 4
#define N_ 4096
#define DIN_ 128

// c = log2(e)/8 ; C2 = c^2 ; exp(dist/8) = exp2(sqrt(d2 * C2))
#define C2_ 0.0325213905f
#define NEG2C2_ (-0.0650427810f)

typedef __attribute__((ext_vector_type(8))) short short8;
typedef __attribute__((ext_vector_type(4))) float f32x4;
typedef __attribute__((ext_vector_type(4))) unsigned short us4;

__device__ __forceinline__ unsigned short f2bf(float f) {
    union { float f; unsigned int i; } v; v.f = f;
    unsigned int i = v.i;
    return (unsigned short)((i + 0x7FFFu + ((i >> 16) & 1u)) >> 16);
}

__device__ __forceinline__ unsigned int cvt_pk_bf16(float lo, float hi) {
    unsigned int r;
    asm("v_cvt_pk_bf16_f32 %0, %1, %2" : "=v"(r) : "v"(lo), "v"(hi));
    return r;
}

// async 16B global->LDS (no VGPR round-trip). lds ptr must be wave-uniform.
__device__ __forceinline__ void gload16(const void* g, void* l) {
    __builtin_amdgcn_global_load_lds(
        (const __attribute__((address_space(1))) void*)g,
        (__attribute__((address_space(3))) void*)l, 16, 0, 0);
}

// ---------------- projection: x[R,128] @ {Wq,Wk,Wv}[128,64] ----------------
// grid (512 row-tiles of 32, 3 projs), 256 threads. W (32KB) + x tile (16.9KB)
// in LDS -> 49.7KB -> 3 blocks/CU; grid 1536 = exactly 2 residency rounds.
__global__ __launch_bounds__(256, 3) void proj_kernel(
    const float* __restrict__ x, const float* __restrict__ Wq,
    const float* __restrict__ Wk, const float* __restrict__ Wv,
    unsigned short* __restrict__ qb, unsigned short* __restrict__ kb,
    unsigned short* __restrict__ vT, float* __restrict__ qsq,
    float* __restrict__ ksq)
{
    __shared__ float xl[32 * 132];     // 16896 B, padded rows
    __shared__ float wl[128 * 64];     // 32768 B
    const int t = threadIdx.x;
    const int R0 = blockIdx.x * 32;
    const int proj = blockIdx.y;
    const float* __restrict__ W = (proj == 0) ? Wq : ((proj == 1) ? Wk : Wv);

#pragma unroll
    for (int j = 0; j < 4; ++j) {
        const int i = t + 256 * j;          // 0..1023
        const int row = i >> 5, dc = i & 31;
        *(float4*)(&xl[row * 132 + dc * 4]) =
            *(const float4*)(x + (size_t)(R0 + row) * DIN_ + dc * 4);
    }
#pragma unroll
    for (int j = 0; j < 8; ++j) {
        const int i = t + 256 * j;
        *(float4*)(&wl[i * 4]) = *(const float4*)(W + (size_t)i * 4);
    }
    __syncthreads();

    const int cg = t & 15, rg = t >> 4;
    const int c0 = cg * 4, r0 = rg * 2;

    float acc[2][4];
#pragma unroll
    for (int r = 0; r < 2; ++r)
#pragma unroll
        for (int c = 0; c < 4; ++c) acc[r][c] = 0.f;

    for (int d4 = 0; d4 < 32; ++d4) {
        float4 xv[2];
#pragma unroll
        for (int r = 0; r < 2; ++r)
            xv[r] = *(const float4*)(&xl[(r0 + r) * 132 + d4 * 4]);
#pragma unroll
        for (int dd = 0; dd < 4; ++dd) {
            const float4 wv = *(const float4*)(&wl[(d4 * 4 + dd) * 64 + c0]);
            const float wc[4] = { wv.x, wv.y, wv.z, wv.w };
#pragma unroll
            for (int r = 0; r < 2; ++r) {
                const float xr = ((const float*)&xv[r])[dd];
#pragma unroll
                for (int c = 0; c < 4; ++c)
                    acc[r][c] = fmaf(xr, wc[c], acc[r][c]);
            }
        }
    }

    if (proj < 2) {
        unsigned short* dst0 = (proj == 0) ? qb : kb;
#pragma unroll
        for (int r = 0; r < 2; ++r) {
            us4 pk = { f2bf(acc[r][0]), f2bf(acc[r][1]),
                       f2bf(acc[r][2]), f2bf(acc[r][3]) };
            *(us4*)(dst0 + (size_t)(R0 + r0 + r) * 64 + c0) = pk;
        }
#pragma unroll
        for (int r = 0; r < 2; ++r) {
            float s = 0.f;
#pragma unroll
            for (int c = 0; c < 4; ++c) s = fmaf(acc[r][c], acc[r][c], s);
            s += __shfl_xor(s, 1);
            s += __shfl_xor(s, 2);
            s += __shfl_xor(s, 4);
            s += __shfl_xor(s, 8);
            if (cg == 0) {
                float* sq = (proj == 0) ? qsq : ksq;
                sq[R0 + r0 + r] = s;
            }
        }
    } else {
        const int bb = R0 >> 12;
        const int n0 = (R0 & (N_ - 1)) + r0;
#pragma unroll
        for (int c = 0; c < 4; ++c) {
            const unsigned int pk =
                (unsigned int)f2bf(acc[0][c]) | ((unsigned int)f2bf(acc[1][c]) << 16);
            *(unsigned int*)(vT + ((size_t)bb * 64 + (c0 + c)) * N_ + n0) = pk;
        }
    }
}

// ---------------- split-K flash attention, swapped QK^T ----------
// grid (64 q-tiles, 4 batch, 8 splits) = 2048 blocks; 256 threads = 4 waves x
// 16 q-rows. K/V double-buffered in LDS via async global_load_lds with
// inverse-swizzled per-lane global source (rule #21: linear dest + inv-swz
// source + swz read). ONE barrier per tile; global latency hides under
// compute; zero prefetch VGPRs (the R3/R7 spill trap).
__global__ __launch_bounds__(256, 3) void attn_kernel(
    const unsigned short* __restrict__ qb, const unsigned short* __restrict__ kb,
    const unsigned short* __restrict__ vT, const float* __restrict__ qsq,
    const float* __restrict__ ksq, float* __restrict__ Opart,
    float* __restrict__ Lpart, int ktn)
{
    __shared__ __align__(16) char smem[16384 + 16384 + 8192 + 512];
    // [0,16K)   : Klds  2 bufs x [64 k][64 d] bf16, XOR-swizzled rows
    // [16K,32K) : Vlds  2 bufs x [64 e][64 k] bf16, XOR-swizzled rows
    // [32K,40K) : Plds  4 waves x [16 q][64 k] bf16, swizzled
    // [40K, +512): ksql 2 bufs x 64 f32, pre-scaled by C2
    char* Plds = smem + 32768;
    float* ksql = (float*)(smem + 40960);

    const int t = threadIdx.x;
    const int w = t >> 6, lane = t & 63, li = lane & 15, g = lane >> 4;
    const int b = blockIdx.y, sp = blockIdx.z;
    const int q0 = blockIdx.x * 64;
    const int kt0 = sp * ktn;
    char* Pw = Plds + w * 2048;

    // Q fragment: lane li holds row (q0+w*16+li), d-slices g*8 and 32+g*8.
    const size_t qoff = ((size_t)b * N_ + q0 + w * 16 + li) * 64;
    const short8 qa0 = *(const short8*)(qb + qoff + g * 8);
    const short8 qa1 = *(const short8*)(qb + qoff + 32 + g * 8);
    const float qsc = qsq[(size_t)b * N_ + q0 + w * 16 + li] * C2_;

    f32x4 oa[4];
#pragma unroll
    for (int i = 0; i < 4; ++i) oa[i] = (f32x4){0.f, 0.f, 0.f, 0.f};
    float lsum = 0.f;

    const unsigned short* kbb = kb + (size_t)b * N_ * 64;
    const unsigned short* vtb = vT + (size_t)b * 64 * N_;
    const float* ksqb = ksq + (size_t)b * N_;

    // inverse-swizzle source lanes: linear LDS byte (chunk j): j*1024 + lane*16
    // maps to row = 8j + (lane>>3), col-chunk cc = (lane&7) ^ (lane>>3).
    const int lrow = lane >> 3;
    const int lcc = (lane & 7) ^ lrow;

    // wave w stages chunks {2w, 2w+1} of K and of V (1KB each, async).
#define STAGE(bufi, kt)                                                          \
    {                                                                            \
        _Pragma("unroll")                                                        \
        for (int jj = 0; jj < 2; ++jj) {                                         \
            const int j = 2 * w + jj;                                            \
            const int row = 8 * j + lrow;                                        \
            gload16(kbb + (size_t)((kt) * 64 + row) * 64 + lcc * 8,              \
                    smem + (bufi) * 8192 + j * 1024);                            \
            gload16(vtb + (size_t)row * N_ + (kt) * 64 + lcc * 8,                \
                    smem + 16384 + (bufi) * 8192 + j * 1024);                    \
        }                                                                        \
    }

    // ---- prologue: stage tile kt0 into buf 0 ----
    STAGE(0, kt0);
    if (t < 64) ksql[t] = ksqb[kt0 * 64 + t] * C2_;
    __syncthreads();   // drains vmcnt (async loads) + lgkmcnt

    int buf = 0;
    for (int ktl = 0; ktl < ktn; ++ktl) {
        const bool more = (ktl + 1 < ktn);
        float ksn = 0.f;
        if (more) {
            STAGE(buf ^ 1, kt0 + ktl + 1);
            if (t < 64) ksn = ksqb[(kt0 + ktl + 1) * 64 + t] * C2_;
        }

        char* Klds = smem + buf * 8192;
        char* Vlds = smem + 16384 + buf * 8192;
        const float* ksqlb = ksql + buf * 64;

        // ---- S^T = K Q^T (swapped): s[r] = S[k=c*16+g*4+r][q=li] ----
#pragma unroll
        for (int c = 0; c < 4; ++c) {
            const int kr = c * 16 + li;
            const int sw = (kr & 7) << 4;
            const short8 kf0 = *(const short8*)(Klds + ((kr * 128 + g * 16) ^ sw));
            const short8 kf1 = *(const short8*)(Klds + ((kr * 128 + 64 + g * 16) ^ sw));
            f32x4 s = (f32x4){0.f, 0.f, 0.f, 0.f};
            __builtin_amdgcn_s_setprio(1);
            s = __builtin_amdgcn_mfma_f32_16x16x32_bf16(kf0, qa0, s, 0, 0, 0);
            s = __builtin_amdgcn_mfma_f32_16x16x32_bf16(kf1, qa1, s, 0, 0, 0);
            __builtin_amdgcn_s_setprio(0);

            const float4 ksc = *(const float4*)(ksqlb + c * 16 + g * 4);
            const float kscv[4] = { ksc.x, ksc.y, ksc.z, ksc.w };
            float p[4];
#pragma unroll
            for (int r = 0; r < 4; ++r) {
                const float d2 = fmaf(NEG2C2_, s[r], qsc + kscv[r]);
                const float ds = __builtin_amdgcn_sqrtf(fmaxf(d2, 0.0f));
                p[r] = exp2f(ds);
                lsum += p[r];
            }
            // packed P write: row li, k-bytes c*32+g*8 .. +7
            uint2 pk;
            pk.x = cvt_pk_bf16(p[0], p[1]);
            pk.y = cvt_pk_bf16(p[2], p[3]);
            *(uint2*)(Pw + ((li * 128 + c * 32 + g * 8) ^ ((li & 7) << 4))) = pk;
        }

        // ---- O += P @ V : A = P[q=li][k g*8+j], B = V frags ----
        const int swp = (li & 7) << 4;
        const short8 pa0 = *(const short8*)(Pw + ((li * 128 + g * 16) ^ swp));
        const short8 pa1 = *(const short8*)(Pw + ((li * 128 + 64 + g * 16) ^ swp));
        __builtin_amdgcn_s_setprio(1);
#pragma unroll
        for (int c2 = 0; c2 < 4; ++c2) {
            const int er = c2 * 16 + li;
            const int swv = (er & 7) << 4;
            const short8 vf0 = *(const short8*)(Vlds + ((er * 128 + g * 16) ^ swv));
            const short8 vf1 = *(const short8*)(Vlds + ((er * 128 + 64 + g * 16) ^ swv));
            oa[c2] = __builtin_amdgcn_mfma_f32_16x16x32_bf16(pa0, vf0, oa[c2], 0, 0, 0);
            oa[c2] = __builtin_amdgcn_mfma_f32_16x16x32_bf16(pa1, vf1, oa[c2], 0, 0, 0);
        }
        __builtin_amdgcn_s_setprio(0);

        if (more && t < 64) ksql[(buf ^ 1) * 64 + t] = ksn;
        __syncthreads();   // readers done with buf; staged buf^1 fully landed
        buf ^= 1;
    }
#undef STAGE

    // ---- write partials (unnormalized) ----
    const size_t obase = ((size_t)sp * B_ + b) * N_;
    lsum += __shfl_xor(lsum, 16);
    lsum += __shfl_xor(lsum, 32);
    if (lane < 16) Lpart[obase + q0 + w * 16 + li] = lsum;
#pragma unroll
    for (int c2 = 0; c2 < 4; ++c2)
#pragma unroll
        for (int r = 0; r < 4; ++r)
            Opart[(obase + q0 + w * 16 + g * 4 + r) * 64 + c2 * 16 + li] = oa[c2][r];
}

// ---------------- combine splits + normalize ----------------
__global__ __launch_bounds__(256) void reduce_kernel(
    const float* __restrict__ Opart, const float* __restrict__ Lpart,
    float* __restrict__ out, int S)
{
    const int idx = blockIdx.x * 256 + threadIdx.x;
    const int rowg = idx >> 4;
    const int e4 = (idx & 15) << 2;
    float l = 0.f;
    float4 o = {0.f, 0.f, 0.f, 0.f};
    for (int s = 0; s < S; ++s) {
        l += Lpart[(size_t)s * (B_ * N_) + rowg];
        const float4 v = *(const float4*)(Opart + ((size_t)s * (B_ * N_) + rowg) * 64 + e4);
        o.x += v.x; o.y += v.y; o.z += v.z; o.w += v.w;
    }
    const float inv = 1.0f / l;
    const float4 res = {o.x * inv, o.y * inv, o.z * inv, o.w * inv};
    *(float4*)(out + (size_t)rowg * 64 + e4) = res;
}

extern "C" void kernel_launch(void* const* d_in, const int* in_sizes, int n_in,
                              void* d_out, int out_size, void* d_ws, size_t ws_size,
                              hipStream_t stream) {
    (void)in_sizes; (void)n_in; (void)out_size;
    const float* x  = (const float*)d_in[0];
    const float* Wq = (const float*)d_in[1];
    const float* Wk = (const float*)d_in[2];
    const float* Wv = (const float*)d_in[3];

    char* ws = (char*)d_ws;
    const size_t MB = 1024 * 1024;
    unsigned short* qb = (unsigned short*)(ws);                 // 2 MB
    unsigned short* kb = (unsigned short*)(ws + 2 * MB);        // 2 MB
    unsigned short* vT = (unsigned short*)(ws + 4 * MB);        // 2 MB
    float* qsq = (float*)(ws + 6 * MB);                         // 64 KB
    float* ksq = (float*)(ws + 6 * MB + 65536);                 // 64 KB
    float* Lpart = (float*)(ws + 6 * MB + 262144);              // <= 512 KB

    int S;
    float* Opart;
    if (ws_size >= 7 * MB + 32 * MB)      { S = 8; Opart = (float*)(ws + 7 * MB); }
    else if (ws_size >= 7 * MB + 16 * MB) { S = 4; Opart = (float*)(ws + 7 * MB); }
    else if (ws_size >= 7 * MB + 8 * MB)  { S = 2; Opart = (float*)(ws + 7 * MB); }
    else if (ws_size >= 7 * MB + 4 * MB)  { S = 1; Opart = (float*)(ws + 7 * MB); }
    else                                  { S = 1; Opart = (float*)d_out; }

    hipLaunchKernelGGL(proj_kernel, dim3(512, 3), dim3(256), 0, stream,
                       x, Wq, Wk, Wv, qb, kb, vT, qsq, ksq);
    hipLaunchKernelGGL(attn_kernel, dim3(64, B_, S), dim3(256), 0, stream,
                       qb, kb, vT, qsq, ksq, Opart, Lpart, 64 / S);
    hipLaunchKernelGGL(reduce_kernel, dim3(1024), dim3(256), 0, stream,
                       Opart, Lpart, (float*)d_out, S);
}

// Round 9
// 67.024 us; speedup vs baseline: 2.1920x; 1.1102x over previous
//
#include <hip/hip_runtime.h>
#include <cstdint>
#include <cstddef>

#define B_ 4
#define N_ 4096
#define DIN_ 128

// c = log2(e)/8 ; C2 = c^2 ; exp(dist/8) = exp2(sqrt(d2 * C2))
#define C2_ 0.0325213905f
#define NEG2C2_ (-0.0650427810f)

typedef __attribute__((ext_vector_type(8))) short short8;
typedef __attribute__((ext_vector_type(4))) float f32x4;
typedef __attribute__((ext_vector_type(4))) unsigned short us4;

__device__ __forceinline__ unsigned short f2bf(float f) {
    union { float f; unsigned int i; } v; v.f = f;
    unsigned int i = v.i;
    return (unsigned short)((i + 0x7FFFu + ((i >> 16) & 1u)) >> 16);
}

__device__ __forceinline__ unsigned int cvt_pk_bf16(float lo, float hi) {
    unsigned int r;
    asm("v_cvt_pk_bf16_f32 %0, %1, %2" : "=v"(r) : "v"(lo), "v"(hi));
    return r;
}

// ---------------- projection: x[R,128] @ {Wq,Wk,Wv}[128,64] ----------------
// grid (256 row-tiles, 3 projs), 256 threads. Whole W (32KB) + x tile (33KB)
// staged in LDS; thread computes 4 rows x 4 cols, FMA-bound. (R5 version.)
__global__ __launch_bounds__(256, 2) void proj_kernel(
    const float* __restrict__ x, const float* __restrict__ Wq,
    const float* __restrict__ Wk, const float* __restrict__ Wv,
    unsigned short* __restrict__ qb, unsigned short* __restrict__ kb,
    unsigned short* __restrict__ vT, float* __restrict__ qsq,
    float* __restrict__ ksq)
{
    __shared__ float xl[64 * 132];
    __shared__ float wl[128 * 64];
    const int t = threadIdx.x;
    const int R0 = blockIdx.x * 64;
    const int proj = blockIdx.y;
    const float* __restrict__ W = (proj == 0) ? Wq : ((proj == 1) ? Wk : Wv);

#pragma unroll
    for (int j = 0; j < 8; ++j) {
        const int i = t + 256 * j;
        const int row = i >> 5, dc = i & 31;
        *(float4*)(&xl[row * 132 + dc * 4]) =
            *(const float4*)(x + (size_t)(R0 + row) * DIN_ + dc * 4);
    }
#pragma unroll
    for (int j = 0; j < 8; ++j) {
        const int i = t + 256 * j;
        *(float4*)(&wl[i * 4]) = *(const float4*)(W + (size_t)i * 4);
    }
    __syncthreads();

    const int cg = t & 15, rg = t >> 4;
    const int c0 = cg * 4, r0 = rg * 4;

    float acc[4][4];
#pragma unroll
    for (int r = 0; r < 4; ++r)
#pragma unroll
        for (int c = 0; c < 4; ++c) acc[r][c] = 0.f;

    for (int d4 = 0; d4 < 32; ++d4) {
        float4 xv[4];
#pragma unroll
        for (int r = 0; r < 4; ++r)
            xv[r] = *(const float4*)(&xl[(r0 + r) * 132 + d4 * 4]);
#pragma unroll
        for (int dd = 0; dd < 4; ++dd) {
            const float4 wv = *(const float4*)(&wl[(d4 * 4 + dd) * 64 + c0]);
            const float wc[4] = { wv.x, wv.y, wv.z, wv.w };
#pragma unroll
            for (int r = 0; r < 4; ++r) {
                const float xr = ((const float*)&xv[r])[dd];
#pragma unroll
                for (int c = 0; c < 4; ++c)
                    acc[r][c] = fmaf(xr, wc[c], acc[r][c]);
            }
        }
    }

    if (proj < 2) {
        unsigned short* dst0 = (proj == 0) ? qb : kb;
#pragma unroll
        for (int r = 0; r < 4; ++r) {
            us4 pk = { f2bf(acc[r][0]), f2bf(acc[r][1]),
                       f2bf(acc[r][2]), f2bf(acc[r][3]) };
            *(us4*)(dst0 + (size_t)(R0 + r0 + r) * 64 + c0) = pk;
        }
#pragma unroll
        for (int r = 0; r < 4; ++r) {
            float s = 0.f;
#pragma unroll
            for (int c = 0; c < 4; ++c) s = fmaf(acc[r][c], acc[r][c], s);
            s += __shfl_xor(s, 1);
            s += __shfl_xor(s, 2);
            s += __shfl_xor(s, 4);
            s += __shfl_xor(s, 8);
            if (cg == 0) {
                float* sq = (proj == 0) ? qsq : ksq;
                sq[R0 + r0 + r] = s;
            }
        }
    } else {
        const int bb = R0 >> 12;
        const int n0 = (R0 & (N_ - 1)) + r0;
#pragma unroll
        for (int c = 0; c < 4; ++c) {
            us4 pk = { f2bf(acc[0][c]), f2bf(acc[1][c]),
                       f2bf(acc[2][c]), f2bf(acc[3][c]) };
            *(us4*)(vT + ((size_t)bb * 64 + (c0 + c)) * N_ + n0) = pk;
        }
    }
}

// ---------------- split-K flash attention, swapped QK^T, 32 q-rows/wave ----
// grid (32 q-tiles, 4 batch, 8 splits) = 1024 blocks = exactly 4/CU;
// 256 threads = 4 waves x 32 q-rows (two 16-row halves h sharing every
// K/V/ksc LDS read -> 0.21 LDS-cyc/score vs 0.35 at 16 q/wave).
// LDS: K 8K + V 8K + P 16K + ksq .25K = 33KB -> 4 blocks/CU, 16 waves/CU.
__global__ __launch_bounds__(256, 4) void attn_kernel(
    const unsigned short* __restrict__ qb, const unsigned short* __restrict__ kb,
    const unsigned short* __restrict__ vT, const float* __restrict__ qsq,
    const float* __restrict__ ksq, float* __restrict__ Opart,
    float* __restrict__ Lpart, int ktn)
{
    __shared__ __align__(16) char smem[8192 * 2 + 16384 + 256];
    char* Klds = smem;                  // [64 k][64 d] bf16, XOR-swizzled rows
    char* Vlds = smem + 8192;           // [64 e][64 k] bf16, XOR-swizzled rows
    char* Plds = smem + 16384;          // 4 waves x [32 q][64 k] bf16, swizzled
    float* ksql = (float*)(smem + 32768);   // 64 f32, pre-scaled by C2

    const int t = threadIdx.x;
    const int w = t >> 6, lane = t & 63, li = lane & 15, g = lane >> 4;
    const int b = blockIdx.y, sp = blockIdx.z;
    const int q0 = blockIdx.x * 128;
    const int kt0 = sp * ktn;
    char* Pw = Plds + w * 4096;

    // Q fragments, two 16-row halves: lane li holds row q0+w*32+h*16+li,
    // d-slices g*8 and 32+g*8. Used as the MFMA *B* operand (swapped).
    const size_t qbase = ((size_t)b * N_ + q0 + w * 32) * 64;
    short8 qa[2][2];
    float qsc[2];
#pragma unroll
    for (int h = 0; h < 2; ++h) {
        qa[h][0] = *(const short8*)(qb + qbase + (size_t)(h * 16 + li) * 64 + g * 8);
        qa[h][1] = *(const short8*)(qb + qbase + (size_t)(h * 16 + li) * 64 + 32 + g * 8);
        qsc[h] = qsq[(size_t)b * N_ + q0 + w * 32 + h * 16 + li] * C2_;
    }

    f32x4 oa[2][4];
    float lsum[2];
#pragma unroll
    for (int h = 0; h < 2; ++h) {
        lsum[h] = 0.f;
#pragma unroll
        for (int i = 0; i < 4; ++i) oa[h][i] = (f32x4){0.f, 0.f, 0.f, 0.f};
    }

    const unsigned short* kbb = kb + (size_t)b * N_ * 64;
    const unsigned short* vtb = vT + (size_t)b * 64 * N_;
    const float* ksqb = ksq + (size_t)b * N_;

    // staging: 512 16B-chunks each for K and V; thread t does 2 of each
    // (rows t>>3 and +32), row-XOR swizzle.
    const int row0 = t >> 3, cc0 = t & 7;
    const int row1 = row0 + 32;
    const int lb0 = (row0 * 128 + cc0 * 16) ^ ((row0 & 7) << 4);
    const int lb1 = (row1 * 128 + cc0 * 16) ^ ((row1 & 7) << 4);

    for (int ktl = 0; ktl < ktn; ++ktl) {
        const int kt = kt0 + ktl;
        *(uint4*)(Klds + lb0) = *(const uint4*)(kbb + (size_t)(kt * 64 + row0) * 64 + cc0 * 8);
        *(uint4*)(Klds + lb1) = *(const uint4*)(kbb + (size_t)(kt * 64 + row1) * 64 + cc0 * 8);
        *(uint4*)(Vlds + lb0) = *(const uint4*)(vtb + (size_t)row0 * N_ + kt * 64 + cc0 * 8);
        *(uint4*)(Vlds + lb1) = *(const uint4*)(vtb + (size_t)row1 * N_ + kt * 64 + cc0 * 8);
        if (t < 64) ksql[t] = ksqb[kt * 64 + t] * C2_;
        __syncthreads();

        // ---- S^T = K Q^T (swapped): s[h][r] = S[k=c*16+g*4+r][q=h*16+li] ----
#pragma unroll
        for (int c = 0; c < 4; ++c) {
            const int kr = c * 16 + li;
            const int sw = (kr & 7) << 4;
            const short8 kf0 = *(const short8*)(Klds + ((kr * 128 + g * 16) ^ sw));
            const short8 kf1 = *(const short8*)(Klds + ((kr * 128 + 64 + g * 16) ^ sw));
            f32x4 s[2];
            __builtin_amdgcn_s_setprio(1);
#pragma unroll
            for (int h = 0; h < 2; ++h) {
                s[h] = (f32x4){0.f, 0.f, 0.f, 0.f};
                s[h] = __builtin_amdgcn_mfma_f32_16x16x32_bf16(kf0, qa[h][0], s[h], 0, 0, 0);
                s[h] = __builtin_amdgcn_mfma_f32_16x16x32_bf16(kf1, qa[h][1], s[h], 0, 0, 0);
            }
            __builtin_amdgcn_s_setprio(0);

            const float4 ksc = *(const float4*)(ksql + c * 16 + g * 4);
            const float kscv[4] = { ksc.x, ksc.y, ksc.z, ksc.w };
#pragma unroll
            for (int h = 0; h < 2; ++h) {
                float p[4];
#pragma unroll
                for (int r = 0; r < 4; ++r) {
                    const float d2 = fmaf(NEG2C2_, s[h][r], qsc[h] + kscv[r]);
                    const float ds = __builtin_amdgcn_sqrtf(fmaxf(d2, 0.0f));
                    p[r] = exp2f(ds);
                    lsum[h] += p[r];
                }
                // packed P write: row h*16+li, k-bytes c*32+g*8 .. +7
                uint2 pk;
                pk.x = cvt_pk_bf16(p[0], p[1]);
                pk.y = cvt_pk_bf16(p[2], p[3]);
                const int prow = h * 16 + li;
                *(uint2*)(Pw + ((prow * 128 + c * 32 + g * 8) ^ ((prow & 7) << 4))) = pk;
            }
        }

        // ---- O += P @ V : A = P[q][k g*8+j], B = V frags (shared across h) --
        short8 pa[2][2];
#pragma unroll
        for (int h = 0; h < 2; ++h) {
            const int pr = h * 16 + li;
            const int swp = (pr & 7) << 4;
            pa[h][0] = *(const short8*)(Pw + ((pr * 128 + g * 16) ^ swp));
            pa[h][1] = *(const short8*)(Pw + ((pr * 128 + 64 + g * 16) ^ swp));
        }
        __builtin_amdgcn_s_setprio(1);
#pragma unroll
        for (int c2 = 0; c2 < 4; ++c2) {
            const int er = c2 * 16 + li;
            const int swv = (er & 7) << 4;
            const short8 vf0 = *(const short8*)(Vlds + ((er * 128 + g * 16) ^ swv));
            const short8 vf1 = *(const short8*)(Vlds + ((er * 128 + 64 + g * 16) ^ swv));
#pragma unroll
            for (int h = 0; h < 2; ++h) {
                oa[h][c2] = __builtin_amdgcn_mfma_f32_16x16x32_bf16(pa[h][0], vf0, oa[h][c2], 0, 0, 0);
                oa[h][c2] = __builtin_amdgcn_mfma_f32_16x16x32_bf16(pa[h][1], vf1, oa[h][c2], 0, 0, 0);
            }
        }
        __builtin_amdgcn_s_setprio(0);
        __syncthreads();
    }

    // ---- write partials (unnormalized) ----
    const size_t obase = ((size_t)sp * B_ + b) * N_;
#pragma unroll
    for (int h = 0; h < 2; ++h) {
        float ls = lsum[h];
        ls += __shfl_xor(ls, 16);
        ls += __shfl_xor(ls, 32);
        if (lane < 16) Lpart[obase + q0 + w * 32 + h * 16 + li] = ls;
#pragma unroll
        for (int c2 = 0; c2 < 4; ++c2)
#pragma unroll
            for (int r = 0; r < 4; ++r)
                Opart[(obase + q0 + w * 32 + h * 16 + g * 4 + r) * 64 + c2 * 16 + li]
                    = oa[h][c2][r];
    }
}

// ---------------- combine splits + normalize ----------------
__global__ __launch_bounds__(256) void reduce_kernel(
    const float* __restrict__ Opart, const float* __restrict__ Lpart,
    float* __restrict__ out, int S)
{
    const int idx = blockIdx.x * 256 + threadIdx.x;
    const int rowg = idx >> 4;
    const int e4 = (idx & 15) << 2;
    float l = 0.f;
    float4 o = {0.f, 0.f, 0.f, 0.f};
    for (int s = 0; s < S; ++s) {
        l += Lpart[(size_t)s * (B_ * N_) + rowg];
        const float4 v = *(const float4*)(Opart + ((size_t)s * (B_ * N_) + rowg) * 64 + e4);
        o.x += v.x; o.y += v.y; o.z += v.z; o.w += v.w;
    }
    const float inv = 1.0f / l;
    const float4 res = {o.x * inv, o.y * inv, o.z * inv, o.w * inv};
    *(float4*)(out + (size_t)rowg * 64 + e4) = res;
}

extern "C" void kernel_launch(void* const* d_in, const int* in_sizes, int n_in,
                              void* d_out, int out_size, void* d_ws, size_t ws_size,
                              hipStream_t stream) {
    (void)in_sizes; (void)n_in; (void)out_size;
    const float* x  = (const float*)d_in[0];
    const float* Wq = (const float*)d_in[1];
    const float* Wk = (const float*)d_in[2];
    const float* Wv = (const float*)d_in[3];

    char* ws = (char*)d_ws;
    const size_t MB = 1024 * 1024;
    unsigned short* qb = (unsigned short*)(ws);                 // 2 MB
    unsigned short* kb = (unsigned short*)(ws + 2 * MB);        // 2 MB
    unsigned short* vT = (unsigned short*)(ws + 4 * MB);        // 2 MB
    float* qsq = (float*)(ws + 6 * MB);                         // 64 KB
    float* ksq = (float*)(ws + 6 * MB + 65536);                 // 64 KB
    float* Lpart = (float*)(ws + 6 * MB + 262144);              // <= 512 KB

    int S;
    float* Opart;
    if (ws_size >= 7 * MB + 32 * MB)      { S = 8; Opart = (float*)(ws + 7 * MB); }
    else if (ws_size >= 7 * MB + 16 * MB) { S = 4; Opart = (float*)(ws + 7 * MB); }
    else if (ws_size >= 7 * MB + 8 * MB)  { S = 2; Opart = (float*)(ws + 7 * MB); }
    else if (ws_size >= 7 * MB + 4 * MB)  { S = 1; Opart = (float*)(ws + 7 * MB); }
    else                                  { S = 1; Opart = (float*)d_out; }

    hipLaunchKernelGGL(proj_kernel, dim3(256, 3), dim3(256), 0, stream,
                       x, Wq, Wk, Wv, qb, kb, vT, qsq, ksq);
    hipLaunchKernelGGL(attn_kernel, dim3(32, B_, S), dim3(256), 0, stream,
                       qb, kb, vT, qsq, ksq, Opart, Lpart, 64 / S);
    hipLaunchKernelGGL(reduce_kernel, dim3(1024), dim3(256), 0, stream,
                       Opart, Lpart, (float*)d_out, S);
}

// Round 10
// 61.451 us; speedup vs baseline: 2.3907x; 1.0907x over previous
//
#include <hip/hip_runtime.h>
#include <cstdint>
#include <cstddef>

#define B_ 4
#define N_ 4096
#define DIN_ 128

// c = log2(e)/8 ; C2 = c^2 ; exp(dist/8) = exp2(sqrt(d2 * C2))
#define C2_ 0.0325213905f
#define NEG2C2_ (-0.0650427810f)

typedef __attribute__((ext_vector_type(8))) short short8;
typedef __attribute__((ext_vector_type(4))) float f32x4;
typedef __attribute__((ext_vector_type(4))) unsigned short us4;
typedef __attribute__((ext_vector_type(4))) unsigned int u32x4;

#if defined(__has_builtin)
#if __has_builtin(__builtin_amdgcn_exp2f)
#define EXP2(x) __builtin_amdgcn_exp2f(x)
#else
#define EXP2(x) exp2f(x)
#endif
#else
#define EXP2(x) exp2f(x)
#endif

__device__ __forceinline__ unsigned short f2bf(float f) {
    union { float f; unsigned int i; } v; v.f = f;
    unsigned int i = v.i;
    return (unsigned short)((i + 0x7FFFu + ((i >> 16) & 1u)) >> 16);
}

__device__ __forceinline__ unsigned int cvt_pk_bf16(float lo, float hi) {
    unsigned int r;
    asm("v_cvt_pk_bf16_f32 %0, %1, %2" : "=v"(r) : "v"(lo), "v"(hi));
    return r;
}

// ---------------- projection: x[R,128] @ {Wq,Wk,Wv}[128,64] ----------------
// grid (256 row-tiles, 3 projs), 256 threads. Whole W (32KB) + x tile (33KB)
// staged in LDS; thread computes 4 rows x 4 cols, FMA-bound. (R5 version.)
__global__ __launch_bounds__(256, 2) void proj_kernel(
    const float* __restrict__ x, const float* __restrict__ Wq,
    const float* __restrict__ Wk, const float* __restrict__ Wv,
    unsigned short* __restrict__ qb, unsigned short* __restrict__ kb,
    unsigned short* __restrict__ vT, float* __restrict__ qsq,
    float* __restrict__ ksq)
{
    __shared__ float xl[64 * 132];
    __shared__ float wl[128 * 64];
    const int t = threadIdx.x;
    const int R0 = blockIdx.x * 64;
    const int proj = blockIdx.y;
    const float* __restrict__ W = (proj == 0) ? Wq : ((proj == 1) ? Wk : Wv);

#pragma unroll
    for (int j = 0; j < 8; ++j) {
        const int i = t + 256 * j;
        const int row = i >> 5, dc = i & 31;
        *(float4*)(&xl[row * 132 + dc * 4]) =
            *(const float4*)(x + (size_t)(R0 + row) * DIN_ + dc * 4);
    }
#pragma unroll
    for (int j = 0; j < 8; ++j) {
        const int i = t + 256 * j;
        *(float4*)(&wl[i * 4]) = *(const float4*)(W + (size_t)i * 4);
    }
    __syncthreads();

    const int cg = t & 15, rg = t >> 4;
    const int c0 = cg * 4, r0 = rg * 4;

    float acc[4][4];
#pragma unroll
    for (int r = 0; r < 4; ++r)
#pragma unroll
        for (int c = 0; c < 4; ++c) acc[r][c] = 0.f;

    for (int d4 = 0; d4 < 32; ++d4) {
        float4 xv[4];
#pragma unroll
        for (int r = 0; r < 4; ++r)
            xv[r] = *(const float4*)(&xl[(r0 + r) * 132 + d4 * 4]);
#pragma unroll
        for (int dd = 0; dd < 4; ++dd) {
            const float4 wv = *(const float4*)(&wl[(d4 * 4 + dd) * 64 + c0]);
            const float wc[4] = { wv.x, wv.y, wv.z, wv.w };
#pragma unroll
            for (int r = 0; r < 4; ++r) {
                const float xr = ((const float*)&xv[r])[dd];
#pragma unroll
                for (int c = 0; c < 4; ++c)
                    acc[r][c] = fmaf(xr, wc[c], acc[r][c]);
            }
        }
    }

    if (proj < 2) {
        unsigned short* dst0 = (proj == 0) ? qb : kb;
#pragma unroll
        for (int r = 0; r < 4; ++r) {
            us4 pk = { f2bf(acc[r][0]), f2bf(acc[r][1]),
                       f2bf(acc[r][2]), f2bf(acc[r][3]) };
            *(us4*)(dst0 + (size_t)(R0 + r0 + r) * 64 + c0) = pk;
        }
#pragma unroll
        for (int r = 0; r < 4; ++r) {
            float s = 0.f;
#pragma unroll
            for (int c = 0; c < 4; ++c) s = fmaf(acc[r][c], acc[r][c], s);
            s += __shfl_xor(s, 1);
            s += __shfl_xor(s, 2);
            s += __shfl_xor(s, 4);
            s += __shfl_xor(s, 8);
            if (cg == 0) {
                float* sq = (proj == 0) ? qsq : ksq;
                sq[R0 + r0 + r] = s;
            }
        }
    } else {
        const int bb = R0 >> 12;
        const int n0 = (R0 & (N_ - 1)) + r0;
#pragma unroll
        for (int c = 0; c < 4; ++c) {
            us4 pk = { f2bf(acc[0][c]), f2bf(acc[1][c]),
                       f2bf(acc[2][c]), f2bf(acc[3][c]) };
            *(us4*)(vT + ((size_t)bb * 64 + (c0 + c)) * N_ + n0) = pk;
        }
    }
}

// ---------------- split-K flash attention, swapped QK^T, 32 q-rows/wave ----
// grid (32 q-tiles, 4 batch, 8 splits) = 1024 blocks = 4/CU; 256 threads =
// 4 waves x 32 q-rows. K-row permutation trick: QK mfma c loads K row
// tau_c(li) = 8(li>>2)+(li&3)+4(c&1)+32(c>>1), so lane (li,g) reg (c,r)
// holds k = 8g+r+4(c&1)+32(c>>1) -> cvt_pk assembles the PV A-fragments
// IN REGISTERS (no P LDS round-trip, no cross-lane). Raw v_exp_f32.
// LDS: K 8K + V 8K + ksq .25K = 16.6KB.
__global__ __launch_bounds__(256, 4) void attn_kernel(
    const unsigned short* __restrict__ qb, const unsigned short* __restrict__ kb,
    const unsigned short* __restrict__ vT, const float* __restrict__ qsq,
    const float* __restrict__ ksq, float* __restrict__ Opart,
    float* __restrict__ Lpart, int ktn)
{
    __shared__ __align__(16) char smem[8192 * 2 + 256];
    char* Klds = smem;                  // [64 k][64 d] bf16, XOR-swizzled rows
    char* Vlds = smem + 8192;           // [64 e][64 k] bf16, XOR-swizzled rows
    float* ksql = (float*)(smem + 16384);   // 64 f32, pre-scaled by C2

    const int t = threadIdx.x;
    const int w = t >> 6, lane = t & 63, li = lane & 15, g = lane >> 4;
    const int b = blockIdx.y, sp = blockIdx.z;
    const int q0 = blockIdx.x * 128;
    const int kt0 = sp * ktn;

    // Q fragments, two 16-row halves (MFMA B operand in swapped product)
    const size_t qbase = ((size_t)b * N_ + q0 + w * 32) * 64;
    short8 qa[2][2];
    float qsc[2];
#pragma unroll
    for (int h = 0; h < 2; ++h) {
        qa[h][0] = *(const short8*)(qb + qbase + (size_t)(h * 16 + li) * 64 + g * 8);
        qa[h][1] = *(const short8*)(qb + qbase + (size_t)(h * 16 + li) * 64 + 32 + g * 8);
        qsc[h] = qsq[(size_t)b * N_ + q0 + w * 32 + h * 16 + li] * C2_;
    }

    f32x4 oa[2][4];
    float lsum[2];
#pragma unroll
    for (int h = 0; h < 2; ++h) {
        lsum[h] = 0.f;
#pragma unroll
        for (int i = 0; i < 4; ++i) oa[h][i] = (f32x4){0.f, 0.f, 0.f, 0.f};
    }

    const unsigned short* kbb = kb + (size_t)b * N_ * 64;
    const unsigned short* vtb = vT + (size_t)b * 64 * N_;
    const float* ksqb = ksq + (size_t)b * N_;

    // staging: 512 16B-chunks each for K and V; thread t does 2 of each
    const int row0 = t >> 3, cc0 = t & 7;
    const int row1 = row0 + 32;
    const int lb0 = (row0 * 128 + cc0 * 16) ^ ((row0 & 7) << 4);
    const int lb1 = (row1 * 128 + cc0 * 16) ^ ((row1 & 7) << 4);

    // permuted K-row base for this lane (c adds {0,4,32,36})
    const int krbase = ((li >> 2) << 3) + (li & 3);

    for (int ktl = 0; ktl < ktn; ++ktl) {
        const int kt = kt0 + ktl;
        *(uint4*)(Klds + lb0) = *(const uint4*)(kbb + (size_t)(kt * 64 + row0) * 64 + cc0 * 8);
        *(uint4*)(Klds + lb1) = *(const uint4*)(kbb + (size_t)(kt * 64 + row1) * 64 + cc0 * 8);
        *(uint4*)(Vlds + lb0) = *(const uint4*)(vtb + (size_t)row0 * N_ + kt * 64 + cc0 * 8);
        *(uint4*)(Vlds + lb1) = *(const uint4*)(vtb + (size_t)row1 * N_ + kt * 64 + cc0 * 8);
        if (t < 64) ksql[t] = ksqb[kt * 64 + t] * C2_;
        __syncthreads();

        // ---- QK^T (swapped, K-rows permuted) + softmax -> register P ----
        u32x4 pa0[2], pa1[2];
#pragma unroll
        for (int c = 0; c < 4; ++c) {
            const int koff = ((c & 1) << 2) + ((c >> 1) << 5);   // {0,4,32,36}
            const int kr = krbase + koff;
            const int sw = (kr & 7) << 4;
            const short8 kf0 = *(const short8*)(Klds + ((kr * 128 + g * 16) ^ sw));
            const short8 kf1 = *(const short8*)(Klds + ((kr * 128 + 64 + g * 16) ^ sw));
            f32x4 s[2];
            __builtin_amdgcn_s_setprio(1);
#pragma unroll
            for (int h = 0; h < 2; ++h) {
                s[h] = (f32x4){0.f, 0.f, 0.f, 0.f};
                s[h] = __builtin_amdgcn_mfma_f32_16x16x32_bf16(kf0, qa[h][0], s[h], 0, 0, 0);
                s[h] = __builtin_amdgcn_mfma_f32_16x16x32_bf16(kf1, qa[h][1], s[h], 0, 0, 0);
            }
            __builtin_amdgcn_s_setprio(0);

            // reg (c,r) holds k = 8g + r + koff
            const float4 ksc = *(const float4*)(ksql + 8 * g + koff);
            const float kscv[4] = { ksc.x, ksc.y, ksc.z, ksc.w };
#pragma unroll
            for (int h = 0; h < 2; ++h) {
                float p[4];
#pragma unroll
                for (int r = 0; r < 4; ++r) {
                    const float d2 = fmaf(NEG2C2_, s[h][r], qsc[h] + kscv[r]);
                    const float ds = __builtin_amdgcn_sqrtf(fmaxf(d2, 0.0f));
                    p[r] = EXP2(ds);
                    lsum[h] += p[r];
                }
                const unsigned int lo = cvt_pk_bf16(p[0], p[1]);
                const unsigned int hi = cvt_pk_bf16(p[2], p[3]);
                if (c == 0)      { pa0[h].x = lo; pa0[h].y = hi; }
                else if (c == 1) { pa0[h].z = lo; pa0[h].w = hi; }
                else if (c == 2) { pa1[h].x = lo; pa1[h].y = hi; }
                else             { pa1[h].z = lo; pa1[h].w = hi; }
            }
        }

        // ---- O += P @ V : A = register pa, B = V frags (shared across h) ----
        short8 paf[2][2];
#pragma unroll
        for (int h = 0; h < 2; ++h) {
            paf[h][0] = __builtin_bit_cast(short8, pa0[h]);
            paf[h][1] = __builtin_bit_cast(short8, pa1[h]);
        }
        __builtin_amdgcn_s_setprio(1);
#pragma unroll
        for (int c2 = 0; c2 < 4; ++c2) {
            const int er = c2 * 16 + li;
            const int swv = (er & 7) << 4;
            const short8 vf0 = *(const short8*)(Vlds + ((er * 128 + g * 16) ^ swv));
            const short8 vf1 = *(const short8*)(Vlds + ((er * 128 + 64 + g * 16) ^ swv));
#pragma unroll
            for (int h = 0; h < 2; ++h) {
                oa[h][c2] = __builtin_amdgcn_mfma_f32_16x16x32_bf16(paf[h][0], vf0, oa[h][c2], 0, 0, 0);
                oa[h][c2] = __builtin_amdgcn_mfma_f32_16x16x32_bf16(paf[h][1], vf1, oa[h][c2], 0, 0, 0);
            }
        }
        __builtin_amdgcn_s_setprio(0);
        __syncthreads();
    }

    // ---- write partials (unnormalized) ----
    const size_t obase = ((size_t)sp * B_ + b) * N_;
#pragma unroll
    for (int h = 0; h < 2; ++h) {
        float ls = lsum[h];
        ls += __shfl_xor(ls, 16);
        ls += __shfl_xor(ls, 32);
        if (lane < 16) Lpart[obase + q0 + w * 32 + h * 16 + li] = ls;
#pragma unroll
        for (int c2 = 0; c2 < 4; ++c2)
#pragma unroll
            for (int r = 0; r < 4; ++r)
                Opart[(obase + q0 + w * 32 + h * 16 + g * 4 + r) * 64 + c2 * 16 + li]
                    = oa[h][c2][r];
    }
}

// ---------------- combine splits + normalize ----------------
__global__ __launch_bounds__(256) void reduce_kernel(
    const float* __restrict__ Opart, const float* __restrict__ Lpart,
    float* __restrict__ out, int S)
{
    const int idx = blockIdx.x * 256 + threadIdx.x;
    const int rowg = idx >> 4;
    const int e4 = (idx & 15) << 2;
    float l = 0.f;
    float4 o = {0.f, 0.f, 0.f, 0.f};
    for (int s = 0; s < S; ++s) {
        l += Lpart[(size_t)s * (B_ * N_) + rowg];
        const float4 v = *(const float4*)(Opart + ((size_t)s * (B_ * N_) + rowg) * 64 + e4);
        o.x += v.x; o.y += v.y; o.z += v.z; o.w += v.w;
    }
    const float inv = 1.0f / l;
    const float4 res = {o.x * inv, o.y * inv, o.z * inv, o.w * inv};
    *(float4*)(out + (size_t)rowg * 64 + e4) = res;
}

extern "C" void kernel_launch(void* const* d_in, const int* in_sizes, int n_in,
                              void* d_out, int out_size, void* d_ws, size_t ws_size,
                              hipStream_t stream) {
    (void)in_sizes; (void)n_in; (void)out_size;
    const float* x  = (const float*)d_in[0];
    const float* Wq = (const float*)d_in[1];
    const float* Wk = (const float*)d_in[2];
    const float* Wv = (const float*)d_in[3];

    char* ws = (char*)d_ws;
    const size_t MB = 1024 * 1024;
    unsigned short* qb = (unsigned short*)(ws);                 // 2 MB
    unsigned short* kb = (unsigned short*)(ws + 2 * MB);        // 2 MB
    unsigned short* vT = (unsigned short*)(ws + 4 * MB);        // 2 MB
    float* qsq = (float*)(ws + 6 * MB);                         // 64 KB
    float* ksq = (float*)(ws + 6 * MB + 65536);                 // 64 KB
    float* Lpart = (float*)(ws + 6 * MB + 262144);              // <= 512 KB

    int S;
    float* Opart;
    if (ws_size >= 7 * MB + 32 * MB)      { S = 8; Opart = (float*)(ws + 7 * MB); }
    else if (ws_size >= 7 * MB + 16 * MB) { S = 4; Opart = (float*)(ws + 7 * MB); }
    else if (ws_size >= 7 * MB + 8 * MB)  { S = 2; Opart = (float*)(ws + 7 * MB); }
    else if (ws_size >= 7 * MB + 4 * MB)  { S = 1; Opart = (float*)(ws + 7 * MB); }
    else                                  { S = 1; Opart = (float*)d_out; }

    hipLaunchKernelGGL(proj_kernel, dim3(256, 3), dim3(256), 0, stream,
                       x, Wq, Wk, Wv, qb, kb, vT, qsq, ksq);
    hipLaunchKernelGGL(attn_kernel, dim3(32, B_, S), dim3(256), 0, stream,
                       qb, kb, vT, qsq, ksq, Opart, Lpart, 64 / S);
    hipLaunchKernelGGL(reduce_kernel, dim3(1024), dim3(256), 0, stream,
                       Opart, Lpart, (float*)d_out, S);
}

// Round 12
// 53.033 us; speedup vs baseline: 2.7702x; 1.1587x over previous
//
#include <hip/hip_runtime.h>
#include <cstdint>
#include <cstddef>

#define B_ 4
#define N_ 4096
#define DIN_ 128

// c = log2(e)/8 ; C2 = c^2 ; exp(dist/8) = exp2(sqrt(d2 * C2))
#define C2_ 0.0325213905f
#define NEG2C2_ (-0.0650427810f)

typedef __attribute__((ext_vector_type(8))) short short8;
typedef __attribute__((ext_vector_type(4))) float f32x4;
typedef __attribute__((ext_vector_type(4))) unsigned short us4;
typedef __attribute__((ext_vector_type(4))) unsigned int u32x4;

#if defined(__has_builtin)
#if __has_builtin(__builtin_amdgcn_exp2f)
#define EXP2(x) __builtin_amdgcn_exp2f(x)
#else
#define EXP2(x) exp2f(x)
#endif
#else
#define EXP2(x) exp2f(x)
#endif

__device__ __forceinline__ unsigned short f2bf(float f) {
    union { float f; unsigned int i; } v; v.f = f;
    unsigned int i = v.i;
    return (unsigned short)((i + 0x7FFFu + ((i >> 16) & 1u)) >> 16);
}

__device__ __forceinline__ unsigned int cvt_pk_bf16(float lo, float hi) {
    unsigned int r;
    asm("v_cvt_pk_bf16_f32 %0, %1, %2" : "=v"(r) : "v"(lo), "v"(hi));
    return r;
}

// ---------------- MFMA projection: x[64 rows,128] @ {Wq,Wk,Wv} -> q,k,vT ----
// grid 256 blocks (64 rows each, ALL 3 projs -> x read once), 256 thr = 4
// waves x 16 rows. LDS: xb bf16 [64][128] swizzled (16K) + 3x wT bf16
// [64 col][128 k] swizzled (48K) = 64KB. Per wave: 4 A-frags reused over
// 3 projs x 4 col-tiles x 4 k-steps = 48 MFMAs. Same D[i][j]=A_i.B_j
// convention as the (bench-verified) attn kernel.
__global__ __launch_bounds__(256, 2) void proj_kernel(
    const float* __restrict__ x, const float* __restrict__ Wq,
    const float* __restrict__ Wk, const float* __restrict__ Wv,
    unsigned short* __restrict__ qb, unsigned short* __restrict__ kb,
    unsigned short* __restrict__ vT, float* __restrict__ qsq,
    float* __restrict__ ksq)
{
    __shared__ __align__(16) char smem[16384 + 3 * 16384];
    char* xb = smem;

    const int t = threadIdx.x;
    const int R0 = blockIdx.x * 64;

    // ---- stage x tile -> bf16, XOR-swizzled rows ----
#pragma unroll
    for (int j = 0; j < 8; ++j) {
        const int i = t + 256 * j;              // 0..2047 float4-chunks
        const int row = i >> 5, c4 = i & 31;
        const float4 v = *(const float4*)(x + (size_t)(R0 + row) * DIN_ + c4 * 4);
        uint2 p2;
        p2.x = cvt_pk_bf16(v.x, v.y);
        p2.y = cvt_pk_bf16(v.z, v.w);
        *(uint2*)(xb + ((row * 256 + c4 * 8) ^ ((row & 7) << 4))) = p2;
    }

    // ---- stage each W transposed -> wT[c][d] bf16, XOR-swizzled ----
    {
        const int c = t & 63, dg = t >> 6;      // dg 0..3 covers d-range dg*32..+32
        const int sw = (c & 7) << 4;
#pragma unroll
        for (int p = 0; p < 3; ++p) {
            const float* __restrict__ Wp = (p == 0) ? Wq : ((p == 1) ? Wk : Wv);
            char* wTp = smem + 16384 + p * 16384;
            float wv[32];
#pragma unroll
            for (int d = 0; d < 32; ++d)
                wv[d] = Wp[(size_t)(dg * 32 + d) * 64 + c];   // coalesced across lanes
            unsigned int pk[16];
#pragma unroll
            for (int i = 0; i < 16; ++i) pk[i] = cvt_pk_bf16(wv[2 * i], wv[2 * i + 1]);
#pragma unroll
            for (int q16 = 0; q16 < 4; ++q16)
                *(uint4*)(wTp + ((c * 256 + dg * 64 + q16 * 16) ^ sw)) =
                    *(const uint4*)&pk[q16 * 4];
        }
    }
    __syncthreads();

    const int w = t >> 6, lane = t & 63, li = lane & 15, g = lane >> 4;

    // A-frags: x row (w*16+li), k-slices s*32 + g*8
    short8 xa[4];
    {
        const int ar = w * 16 + li;
        const int swa = (ar & 7) << 4;
#pragma unroll
        for (int s = 0; s < 4; ++s)
            xa[s] = *(const short8*)(xb + ((ar * 256 + s * 64 + g * 16) ^ swa));
    }

    f32x4 acc[3][4];
#pragma unroll
    for (int p = 0; p < 3; ++p)
#pragma unroll
        for (int c2 = 0; c2 < 4; ++c2) acc[p][c2] = (f32x4){0.f, 0.f, 0.f, 0.f};

#pragma unroll
    for (int p = 0; p < 3; ++p) {
        char* wTp = smem + 16384 + p * 16384;
#pragma unroll
        for (int c2 = 0; c2 < 4; ++c2) {
            const int br = c2 * 16 + li;
            const int swb = (br & 7) << 4;
#pragma unroll
            for (int s = 0; s < 4; ++s) {
                const short8 wb = *(const short8*)(wTp + ((br * 256 + s * 64 + g * 16) ^ swb));
                acc[p][c2] = __builtin_amdgcn_mfma_f32_16x16x32_bf16(xa[s], wb, acc[p][c2], 0, 0, 0);
            }
        }
    }

    // ---- stores: D row (g*4+r) = x row w*16+g*4+r, D col = c2*16+li ----
    const int rbase = R0 + w * 16 + g * 4;
#pragma unroll
    for (int p = 0; p < 2; ++p) {
        unsigned short* dst = (p == 0) ? qb : kb;
#pragma unroll
        for (int c2 = 0; c2 < 4; ++c2)
#pragma unroll
            for (int r = 0; r < 4; ++r)
                dst[(size_t)(rbase + r) * 64 + c2 * 16 + li] = f2bf(acc[p][c2][r]);
        // row squared-norms from the f32 acc
#pragma unroll
        for (int r = 0; r < 4; ++r) {
            float s = 0.f;
#pragma unroll
            for (int c2 = 0; c2 < 4; ++c2)
                s = fmaf(acc[p][c2][r], acc[p][c2][r], s);
            s += __shfl_xor(s, 1);
            s += __shfl_xor(s, 2);
            s += __shfl_xor(s, 4);
            s += __shfl_xor(s, 8);
            if (li == 0) {
                float* sq = (p == 0) ? qsq : ksq;
                sq[rbase + r] = s;
            }
        }
    }
    // v: store transposed vT[b][e][n], 4 consecutive n per us4
    {
        const int bb = R0 >> 12;
        const int n0 = (R0 & (N_ - 1)) + w * 16 + g * 4;
#pragma unroll
        for (int c2 = 0; c2 < 4; ++c2) {
            us4 pk = { f2bf(acc[2][c2][0]), f2bf(acc[2][c2][1]),
                       f2bf(acc[2][c2][2]), f2bf(acc[2][c2][3]) };
            *(us4*)(vT + ((size_t)bb * 64 + c2 * 16 + li) * N_ + n0) = pk;
        }
    }
}

// ---------------- split-K flash attention, swapped QK^T, 32 q-rows/wave ----
// (EXACT R10 kernel — passed at 39.2 us.) grid (32,4,8) = 1024 blocks = 4/CU;
// 256 threads = 4 waves x 32 q-rows. In-register P via K-row permutation.
__global__ __launch_bounds__(256, 4) void attn_kernel(
    const unsigned short* __restrict__ qb, const unsigned short* __restrict__ kb,
    const unsigned short* __restrict__ vT, const float* __restrict__ qsq,
    const float* __restrict__ ksq, float* __restrict__ Opart,
    float* __restrict__ Lpart, int ktn)
{
    __shared__ __align__(16) char smem[8192 * 2 + 256];
    char* Klds = smem;                  // [64 k][64 d] bf16, XOR-swizzled rows
    char* Vlds = smem + 8192;           // [64 e][64 k] bf16, XOR-swizzled rows
    float* ksql = (float*)(smem + 16384);   // 64 f32, pre-scaled by C2

    const int t = threadIdx.x;
    const int w = t >> 6, lane = t & 63, li = lane & 15, g = lane >> 4;
    const int b = blockIdx.y, sp = blockIdx.z;
    const int q0 = blockIdx.x * 128;
    const int kt0 = sp * ktn;

    const size_t qbase = ((size_t)b * N_ + q0 + w * 32) * 64;
    short8 qa[2][2];
    float qsc[2];
#pragma unroll
    for (int h = 0; h < 2; ++h) {
        qa[h][0] = *(const short8*)(qb + qbase + (size_t)(h * 16 + li) * 64 + g * 8);
        qa[h][1] = *(const short8*)(qb + qbase + (size_t)(h * 16 + li) * 64 + 32 + g * 8);
        qsc[h] = qsq[(size_t)b * N_ + q0 + w * 32 + h * 16 + li] * C2_;
    }

    f32x4 oa[2][4];
    float lsum[2];
#pragma unroll
    for (int h = 0; h < 2; ++h) {
        lsum[h] = 0.f;
#pragma unroll
        for (int i = 0; i < 4; ++i) oa[h][i] = (f32x4){0.f, 0.f, 0.f, 0.f};
    }

    const unsigned short* kbb = kb + (size_t)b * N_ * 64;
    const unsigned short* vtb = vT + (size_t)b * 64 * N_;
    const float* ksqb = ksq + (size_t)b * N_;

    const int row0 = t >> 3, cc0 = t & 7;
    const int row1 = row0 + 32;
    const int lb0 = (row0 * 128 + cc0 * 16) ^ ((row0 & 7) << 4);
    const int lb1 = (row1 * 128 + cc0 * 16) ^ ((row1 & 7) << 4);

    const int krbase = ((li >> 2) << 3) + (li & 3);

    for (int ktl = 0; ktl < ktn; ++ktl) {
        const int kt = kt0 + ktl;
        *(uint4*)(Klds + lb0) = *(const uint4*)(kbb + (size_t)(kt * 64 + row0) * 64 + cc0 * 8);
        *(uint4*)(Klds + lb1) = *(const uint4*)(kbb + (size_t)(kt * 64 + row1) * 64 + cc0 * 8);
        *(uint4*)(Vlds + lb0) = *(const uint4*)(vtb + (size_t)row0 * N_ + kt * 64 + cc0 * 8);
        *(uint4*)(Vlds + lb1) = *(const uint4*)(vtb + (size_t)row1 * N_ + kt * 64 + cc0 * 8);
        if (t < 64) ksql[t] = ksqb[kt * 64 + t] * C2_;
        __syncthreads();

        u32x4 pa0[2], pa1[2];
#pragma unroll
        for (int c = 0; c < 4; ++c) {
            const int koff = ((c & 1) << 2) + ((c >> 1) << 5);   // {0,4,32,36}
            const int kr = krbase + koff;
            const int sw = (kr & 7) << 4;
            const short8 kf0 = *(const short8*)(Klds + ((kr * 128 + g * 16) ^ sw));
            const short8 kf1 = *(const short8*)(Klds + ((kr * 128 + 64 + g * 16) ^ sw));
            f32x4 s[2];
            __builtin_amdgcn_s_setprio(1);
#pragma unroll
            for (int h = 0; h < 2; ++h) {
                s[h] = (f32x4){0.f, 0.f, 0.f, 0.f};
                s[h] = __builtin_amdgcn_mfma_f32_16x16x32_bf16(kf0, qa[h][0], s[h], 0, 0, 0);
                s[h] = __builtin_amdgcn_mfma_f32_16x16x32_bf16(kf1, qa[h][1], s[h], 0, 0, 0);
            }
            __builtin_amdgcn_s_setprio(0);

            const float4 ksc = *(const float4*)(ksql + 8 * g + koff);
            const float kscv[4] = { ksc.x, ksc.y, ksc.z, ksc.w };
#pragma unroll
            for (int h = 0; h < 2; ++h) {
                float p[4];
#pragma unroll
                for (int r = 0; r < 4; ++r) {
                    const float d2 = fmaf(NEG2C2_, s[h][r], qsc[h] + kscv[r]);
                    const float ds = __builtin_amdgcn_sqrtf(fmaxf(d2, 0.0f));
                    p[r] = EXP2(ds);
                    lsum[h] += p[r];
                }
                const unsigned int lo = cvt_pk_bf16(p[0], p[1]);
                const unsigned int hi = cvt_pk_bf16(p[2], p[3]);
                if (c == 0)      { pa0[h].x = lo; pa0[h].y = hi; }
                else if (c == 1) { pa0[h].z = lo; pa0[h].w = hi; }
                else if (c == 2) { pa1[h].x = lo; pa1[h].y = hi; }
                else             { pa1[h].z = lo; pa1[h].w = hi; }
            }
        }

        short8 paf[2][2];
#pragma unroll
        for (int h = 0; h < 2; ++h) {
            paf[h][0] = __builtin_bit_cast(short8, pa0[h]);
            paf[h][1] = __builtin_bit_cast(short8, pa1[h]);
        }
        __builtin_amdgcn_s_setprio(1);
#pragma unroll
        for (int c2 = 0; c2 < 4; ++c2) {
            const int er = c2 * 16 + li;
            const int swv = (er & 7) << 4;
            const short8 vf0 = *(const short8*)(Vlds + ((er * 128 + g * 16) ^ swv));
            const short8 vf1 = *(const short8*)(Vlds + ((er * 128 + 64 + g * 16) ^ swv));
#pragma unroll
            for (int h = 0; h < 2; ++h) {
                oa[h][c2] = __builtin_amdgcn_mfma_f32_16x16x32_bf16(paf[h][0], vf0, oa[h][c2], 0, 0, 0);
                oa[h][c2] = __builtin_amdgcn_mfma_f32_16x16x32_bf16(paf[h][1], vf1, oa[h][c2], 0, 0, 0);
            }
        }
        __builtin_amdgcn_s_setprio(0);
        __syncthreads();
    }

    const size_t obase = ((size_t)sp * B_ + b) * N_;
#pragma unroll
    for (int h = 0; h < 2; ++h) {
        float ls = lsum[h];
        ls += __shfl_xor(ls, 16);
        ls += __shfl_xor(ls, 32);
        if (lane < 16) Lpart[obase + q0 + w * 32 + h * 16 + li] = ls;
#pragma unroll
        for (int c2 = 0; c2 < 4; ++c2)
#pragma unroll
            for (int r = 0; r < 4; ++r)
                Opart[(obase + q0 + w * 32 + h * 16 + g * 4 + r) * 64 + c2 * 16 + li]
                    = oa[h][c2][r];
    }
}

// ---------------- combine splits + normalize (R10 f32 version) ----------
__global__ __launch_bounds__(256) void reduce_kernel(
    const float* __restrict__ Opart, const float* __restrict__ Lpart,
    float* __restrict__ out, int S)
{
    const int idx = blockIdx.x * 256 + threadIdx.x;
    const int rowg = idx >> 4;
    const int e4 = (idx & 15) << 2;
    float l = 0.f;
    float4 o = {0.f, 0.f, 0.f, 0.f};
    for (int s = 0; s < S; ++s) {
        l += Lpart[(size_t)s * (B_ * N_) + rowg];
        const float4 v = *(const float4*)(Opart + ((size_t)s * (B_ * N_) + rowg) * 64 + e4);
        o.x += v.x; o.y += v.y; o.z += v.z; o.w += v.w;
    }
    const float inv = 1.0f / l;
    const float4 res = {o.x * inv, o.y * inv, o.z * inv, o.w * inv};
    *(float4*)(out + (size_t)rowg * 64 + e4) = res;
}

extern "C" void kernel_launch(void* const* d_in, const int* in_sizes, int n_in,
                              void* d_out, int out_size, void* d_ws, size_t ws_size,
                              hipStream_t stream) {
    (void)in_sizes; (void)n_in; (void)out_size;
    const float* x  = (const float*)d_in[0];
    const float* Wq = (const float*)d_in[1];
    const float* Wk = (const float*)d_in[2];
    const float* Wv = (const float*)d_in[3];

    char* ws = (char*)d_ws;
    const size_t MB = 1024 * 1024;
    unsigned short* qb = (unsigned short*)(ws);                 // 2 MB
    unsigned short* kb = (unsigned short*)(ws + 2 * MB);        // 2 MB
    unsigned short* vT = (unsigned short*)(ws + 4 * MB);        // 2 MB
    float* qsq = (float*)(ws + 6 * MB);                         // 64 KB
    float* ksq = (float*)(ws + 6 * MB + 65536);                 // 64 KB
    float* Lpart = (float*)(ws + 6 * MB + 262144);              // <= 512 KB

    int S;
    float* Opart;
    if (ws_size >= 7 * MB + 32 * MB)      { S = 8; Opart = (float*)(ws + 7 * MB); }
    else if (ws_size >= 7 * MB + 16 * MB) { S = 4; Opart = (float*)(ws + 7 * MB); }
    else if (ws_size >= 7 * MB + 8 * MB)  { S = 2; Opart = (float*)(ws + 7 * MB); }
    else if (ws_size >= 7 * MB + 4 * MB)  { S = 1; Opart = (float*)(ws + 7 * MB); }
    else                                  { S = 1; Opart = (float*)d_out; }

    hipLaunchKernelGGL(proj_kernel, dim3(256), dim3(256), 0, stream,
                       x, Wq, Wk, Wv, qb, kb, vT, qsq, ksq);
    hipLaunchKernelGGL(attn_kernel, dim3(32, B_, S), dim3(256), 0, stream,
                       qb, kb, vT, qsq, ksq, Opart, Lpart, 64 / S);
    hipLaunchKernelGGL(reduce_kernel, dim3(1024), dim3(256), 0, stream,
                       Opart, Lpart, (float*)d_out, S);
}